// Round 1
// baseline (35.801 us; speedup 1.0000x reference)
//
#include <hip/hip_runtime.h>
#include <math.h>

namespace {
constexpr int kB = 8;
constexpr int kP = 8000;
constexpr int kG = 100;
constexpr int kT = kP + kG;     // 8100
constexpr int kC = 81;
constexpr int kBlk = 256;
constexpr int kBlocksPerBatch = (kT + kBlk - 1) / kBlk;  // 32
constexpr int kNBlk = kB * kBlocksPerBatch;              // 256
constexpr float kFG = 0.5f;
constexpr float kBG = 0.4f;
constexpr float kBeta = 1.0f / 9.0f;
}

// Per-row: IoU match vs 100 gt (LDS-staged), label thresholds, CE via online
// logsumexp, class-gathered smooth-L1, score L1 (target == matched IoU).
// Writes 5 partial sums per block: {nll, sl1, score_l1, n_valid, n_pos}.
__global__ __launch_bounds__(kBlk) void roi_partials(
    const float* __restrict__ proposals,    // [B,P,4]
    const float* __restrict__ gt_boxes,     // [B,G,4]
    const int*   __restrict__ gt_labels,    // [B,G]
    const float* __restrict__ class_logits, // [B,T,C]
    const float* __restrict__ box_reg,      // [B,T,C*4]
    const float* __restrict__ box_scores,   // [B,T]
    float* __restrict__ partials)           // [kNBlk,5]
{
  __shared__ float4 s_gt[kG];
  __shared__ float  s_area[kG];
  __shared__ int    s_lab[kG];
  __shared__ float  s_red[kBlk / 64][5];

  const int b = blockIdx.y;
  const int t = blockIdx.x * kBlk + threadIdx.x;

  for (int i = threadIdx.x; i < kG; i += kBlk) {
    const float4 g = reinterpret_cast<const float4*>(gt_boxes)[(size_t)b * kG + i];
    s_gt[i] = g;
    s_area[i] = (g.z - g.x) * (g.w - g.y);
    s_lab[i] = gt_labels[b * kG + i];
  }
  __syncthreads();

  float v_nll = 0.f, v_sl1 = 0.f, v_sc = 0.f, v_cv = 0.f, v_cp = 0.f;

  if (t < kT) {
    const float4 pb = (t < kP)
        ? reinterpret_cast<const float4*>(proposals)[(size_t)b * kP + t]
        : s_gt[t - kP];
    const float area_p = (pb.z - pb.x) * (pb.w - pb.y);

    // argmax IoU over gt; strict > keeps first max (jnp.argmax semantics)
    float best = -1.f;
    int bi = 0;
    #pragma unroll 4
    for (int g = 0; g < kG; ++g) {
      const float4 gb = s_gt[g];
      float w = fminf(gb.z, pb.z) - fmaxf(gb.x, pb.x);
      float h = fminf(gb.w, pb.w) - fmaxf(gb.y, pb.y);
      w = fmaxf(w, 0.f);
      h = fmaxf(h, 0.f);
      const float inter = w * h;
      const float iou = inter / (s_area[g] + area_p - inter);
      if (iou > best) { best = iou; bi = g; }
    }

    int label = s_lab[bi];
    if (best < kBG) label = 0;          // background
    else if (best < kFG) label = -1;    // ignore
    const bool valid = label >= 0;
    const bool pos = label > 0;
    const int lab = valid ? label : 0;  // clip(labels, 0, C-1)

    if (valid) {
      // online logsumexp over the 81 logits (one expf/iter after max settles)
      const float* lg = class_logits + (size_t)(b * kT + t) * kC;
      float m = -INFINITY, s = 0.f, xl = 0.f;
      for (int c = 0; c < kC; ++c) {
        const float x = lg[c];
        if (c == lab) xl = x;
        if (x > m) {
          s = s * expf(m - x) + 1.f;  // expf(-inf)=0 handles first iter
          m = x;
        } else {
          s += expf(x - m);
        }
      }
      v_nll = -(xl - m - logf(s));
      v_cv = 1.f;
    }

    if (pos) {
      const float4 gb = s_gt[bi];
      // encode_boxes(matched_gt, proposal), weights (10,10,5,5)
      const float ex_w = pb.z - pb.x, ex_h = pb.w - pb.y;
      const float ex_cx = pb.x + 0.5f * ex_w, ex_cy = pb.y + 0.5f * ex_h;
      const float gt_w = gb.z - gb.x, gt_h = gb.w - gb.y;
      const float gt_cx = gb.x + 0.5f * gt_w, gt_cy = gb.y + 0.5f * gt_h;
      const float tx = 10.f * (gt_cx - ex_cx) / ex_w;
      const float ty = 10.f * (gt_cy - ex_cy) / ex_h;
      const float tw = 5.f * logf(gt_w / ex_w);
      const float th = 5.f * logf(gt_h / ex_h);
      // class-specific 4-float gather (16B aligned)
      const float4 pv =
          reinterpret_cast<const float4*>(box_reg)[(size_t)(b * kT + t) * kC + lab];
      const float d0 = fabsf(pv.x - tx), d1 = fabsf(pv.y - ty);
      const float d2 = fabsf(pv.z - tw), d3 = fabsf(pv.w - th);
      float acc = 0.f;
      acc += (d0 < kBeta) ? 0.5f * d0 * d0 / kBeta : d0 - 0.5f * kBeta;
      acc += (d1 < kBeta) ? 0.5f * d1 * d1 / kBeta : d1 - 0.5f * kBeta;
      acc += (d2 < kBeta) ? 0.5f * d2 * d2 / kBeta : d2 - 0.5f * kBeta;
      acc += (d3 < kBeta) ? 0.5f * d3 * d3 / kBeta : d3 - 0.5f * kBeta;
      v_sl1 = acc;
      // score target == matched IoU (elementwise_iou(matched_gt, prop) == best)
      v_sc = fabsf(box_scores[b * kT + t] - best);
      v_cp = 1.f;
    }
  }

  // deterministic block reduction: wave shuffle -> LDS -> thread 0
  float vals[5] = {v_nll, v_sl1, v_sc, v_cv, v_cp};
  #pragma unroll
  for (int off = 32; off > 0; off >>= 1) {
    #pragma unroll
    for (int j = 0; j < 5; ++j) vals[j] += __shfl_down(vals[j], off, 64);
  }
  const int wave = threadIdx.x >> 6, lane = threadIdx.x & 63;
  if (lane == 0) {
    #pragma unroll
    for (int j = 0; j < 5; ++j) s_red[wave][j] = vals[j];
  }
  __syncthreads();
  if (threadIdx.x == 0) {
    const int blk = blockIdx.y * gridDim.x + blockIdx.x;
    #pragma unroll
    for (int j = 0; j < 5; ++j) {
      float tot = 0.f;
      #pragma unroll
      for (int w = 0; w < kBlk / 64; ++w) tot += s_red[w][j];
      partials[blk * 5 + j] = tot;
    }
  }
}

__global__ __launch_bounds__(256) void roi_finalize(
    const float* __restrict__ partials, float* __restrict__ out) {
  __shared__ float s_red[4][5];
  float vals[5] = {0.f, 0.f, 0.f, 0.f, 0.f};
  if (threadIdx.x < kNBlk) {
    #pragma unroll
    for (int j = 0; j < 5; ++j) vals[j] = partials[threadIdx.x * 5 + j];
  }
  #pragma unroll
  for (int off = 32; off > 0; off >>= 1) {
    #pragma unroll
    for (int j = 0; j < 5; ++j) vals[j] += __shfl_down(vals[j], off, 64);
  }
  const int wave = threadIdx.x >> 6, lane = threadIdx.x & 63;
  if (lane == 0) {
    #pragma unroll
    for (int j = 0; j < 5; ++j) s_red[wave][j] = vals[j];
  }
  __syncthreads();
  if (threadIdx.x == 0) {
    float tot[5];
    #pragma unroll
    for (int j = 0; j < 5; ++j)
      tot[j] = s_red[0][j] + s_red[1][j] + s_red[2][j] + s_red[3][j];
    const float nv = fmaxf(tot[3], 1.f);
    const float np = fmaxf(tot[4], 1.f);
    out[0] = tot[0] / nv;  // cls_loss
    out[1] = tot[1] / nv;  // box_loss (ref divides by n_valid)
    out[2] = tot[2] / np;  // score_loss
  }
}

extern "C" void kernel_launch(void* const* d_in, const int* in_sizes, int n_in,
                              void* d_out, int out_size, void* d_ws, size_t ws_size,
                              hipStream_t stream) {
  (void)in_sizes; (void)n_in; (void)out_size; (void)ws_size;
  const float* proposals    = (const float*)d_in[0];
  const float* gt_boxes     = (const float*)d_in[1];
  const int*   gt_labels    = (const int*)d_in[2];
  const float* class_logits = (const float*)d_in[3];
  const float* box_reg      = (const float*)d_in[4];
  const float* box_scores   = (const float*)d_in[5];
  float* partials = (float*)d_ws;   // kNBlk*5 floats = 5120 B
  float* out = (float*)d_out;

  dim3 grid(kBlocksPerBatch, kB);
  roi_partials<<<grid, kBlk, 0, stream>>>(proposals, gt_boxes, gt_labels,
                                          class_logits, box_reg, box_scores,
                                          partials);
  roi_finalize<<<1, 256, 0, stream>>>(partials, out);
}

// Round 2
// 25.844 us; speedup vs baseline: 1.3853x; 1.3853x over previous
//
#include <hip/hip_runtime.h>
#include <math.h>

namespace {
constexpr int kB = 8;
constexpr int kP = 8000;
constexpr int kG = 100;
constexpr int kT = kP + kG;     // 8100
constexpr int kC = 81;
constexpr int kBlk = 256;
constexpr int kLanes = 16;                         // lanes per row-group
constexpr int kRowsPerBlk = kBlk / kLanes;         // 16 rows per block
constexpr int kRows = kB * kT;                     // 64800
constexpr int kNBlk = kRows / kRowsPerBlk;         // 4050 blocks
constexpr float kFG = 0.5f;
constexpr float kBG = 0.4f;
constexpr float kBeta = 1.0f / 9.0f;
}

// One 16-lane group per row: cooperative IoU argmax over 100 gt, cooperative
// CE logsumexp over 81 classes (coalesced 64B-segment loads), lane0 does the
// box encode / score L1. Block writes 5 partial sums.
__global__ __launch_bounds__(kBlk) void roi_partials(
    const float* __restrict__ proposals,    // [B,P,4]
    const float* __restrict__ gt_boxes,     // [B,G,4]
    const int*   __restrict__ gt_labels,    // [B,G]
    const float* __restrict__ class_logits, // [B,T,C]
    const float* __restrict__ box_reg,      // [B,T,C*4]
    const float* __restrict__ box_scores,   // [B,T]
    float* __restrict__ partials)           // [kNBlk,5]
{
  __shared__ float s_red[kBlk / 64][5];

  const int l   = threadIdx.x & (kLanes - 1);
  const int grp = threadIdx.x >> 4;
  const int r   = blockIdx.x * kRowsPerBlk + grp;   // global row, < kRows
  const int b   = r / kT;
  const int t   = r - b * kT;

  const float4* gtb4 = reinterpret_cast<const float4*>(gt_boxes) + (size_t)b * kG;

  // proposal box for this row (rows >= kP are the appended gt boxes)
  const float4 pb = (t < kP)
      ? reinterpret_cast<const float4*>(proposals)[(size_t)b * kP + t]
      : gtb4[t - kP];
  const float area_p = (pb.z - pb.x) * (pb.w - pb.y);

  // --- cooperative IoU argmax over kG gt boxes ---
  float best = -1.f;
  int bi = 0;
  #pragma unroll
  for (int k = 0; k < (kG + kLanes - 1) / kLanes; ++k) {
    const int g = l + k * kLanes;
    if (g < kG) {
      const float4 gb = gtb4[g];
      const float area_g = (gb.z - gb.x) * (gb.w - gb.y);
      float w = fminf(gb.z, pb.z) - fmaxf(gb.x, pb.x);
      float h = fminf(gb.w, pb.w) - fmaxf(gb.y, pb.y);
      w = fmaxf(w, 0.f);
      h = fmaxf(h, 0.f);
      const float inter = w * h;
      const float iou = inter / (area_g + area_p - inter);
      if (iou > best) { best = iou; bi = g; }  // strict >: first-max per lane
    }
  }
  // group argmax reduce, tie-break to smaller index (jnp.argmax first-max)
  #pragma unroll
  for (int m = 8; m >= 1; m >>= 1) {
    const float ob = __shfl_xor(best, m, kLanes);
    const int   oi = __shfl_xor(bi, m, kLanes);
    if (ob > best || (ob == best && oi < bi)) { best = ob; bi = oi; }
  }

  // label logic (same on all 16 lanes; gt_labels read is a broadcast)
  int label = gt_labels[b * kG + bi];
  if (best < kBG) label = 0;
  else if (best < kFG) label = -1;
  const bool valid = label >= 0;
  const bool pos = label > 0;
  const int lab = valid ? label : 0;

  // --- cooperative CE: logsumexp over 81 logits ---
  float v_nll = 0.f, v_cv = 0.f;
  if (valid) {
    const float* lg = class_logits + (size_t)r * kC;
    float x[6];
    float mx = -INFINITY, xl = 0.f;
    #pragma unroll
    for (int k = 0; k < 6; ++k) {
      const int c = l + k * kLanes;
      x[k] = (c < kC) ? lg[c] : -INFINITY;
      mx = fmaxf(mx, x[k]);
      if (c < kC && c == lab) xl = x[k];
    }
    #pragma unroll
    for (int m = 8; m >= 1; m >>= 1) mx = fmaxf(mx, __shfl_xor(mx, m, kLanes));
    float se = 0.f;
    #pragma unroll
    for (int k = 0; k < 6; ++k) se += expf(x[k] - mx);  // exp(-inf)=0 pads
    #pragma unroll
    for (int m = 8; m >= 1; m >>= 1) {
      se += __shfl_xor(se, m, kLanes);
      xl += __shfl_xor(xl, m, kLanes);
    }
    v_nll = -(xl - mx - logf(se));
    v_cv = 1.f;
  }

  // --- box regression + score (lane-0 work) ---
  float v_sl1 = 0.f, v_sc = 0.f, v_cp = 0.f;
  if (pos && l == 0) {
    const float4 gb = gtb4[bi];
    const float ex_w = pb.z - pb.x, ex_h = pb.w - pb.y;
    const float ex_cx = pb.x + 0.5f * ex_w, ex_cy = pb.y + 0.5f * ex_h;
    const float gt_w = gb.z - gb.x, gt_h = gb.w - gb.y;
    const float gt_cx = gb.x + 0.5f * gt_w, gt_cy = gb.y + 0.5f * gt_h;
    const float tx = 10.f * (gt_cx - ex_cx) / ex_w;
    const float ty = 10.f * (gt_cy - ex_cy) / ex_h;
    const float tw = 5.f * logf(gt_w / ex_w);
    const float th = 5.f * logf(gt_h / ex_h);
    const float4 pv =
        reinterpret_cast<const float4*>(box_reg)[(size_t)r * kC + lab];
    const float d0 = fabsf(pv.x - tx), d1 = fabsf(pv.y - ty);
    const float d2 = fabsf(pv.z - tw), d3 = fabsf(pv.w - th);
    float acc = 0.f;
    acc += (d0 < kBeta) ? 0.5f * d0 * d0 / kBeta : d0 - 0.5f * kBeta;
    acc += (d1 < kBeta) ? 0.5f * d1 * d1 / kBeta : d1 - 0.5f * kBeta;
    acc += (d2 < kBeta) ? 0.5f * d2 * d2 / kBeta : d2 - 0.5f * kBeta;
    acc += (d3 < kBeta) ? 0.5f * d3 * d3 / kBeta : d3 - 0.5f * kBeta;
    v_sl1 = acc;
    v_sc = fabsf(box_scores[r] - best);  // score target == matched IoU
    v_cp = 1.f;
  }
  // keep per-row scalars on lane 0 only (CE values are replicated on lanes)
  if (l != 0) { v_nll = 0.f; v_cv = 0.f; }

  // deterministic block reduction
  float vals[5] = {v_nll, v_sl1, v_sc, v_cv, v_cp};
  #pragma unroll
  for (int off = 32; off > 0; off >>= 1) {
    #pragma unroll
    for (int j = 0; j < 5; ++j) vals[j] += __shfl_down(vals[j], off, 64);
  }
  const int wave = threadIdx.x >> 6, lane = threadIdx.x & 63;
  if (lane == 0) {
    #pragma unroll
    for (int j = 0; j < 5; ++j) s_red[wave][j] = vals[j];
  }
  __syncthreads();
  if (threadIdx.x == 0) {
    #pragma unroll
    for (int j = 0; j < 5; ++j) {
      float tot = 0.f;
      #pragma unroll
      for (int w = 0; w < kBlk / 64; ++w) tot += s_red[w][j];
      partials[blockIdx.x * 5 + j] = tot;
    }
  }
}

__global__ __launch_bounds__(256) void roi_finalize(
    const float* __restrict__ partials, float* __restrict__ out) {
  __shared__ float s_red[4][5];
  float vals[5] = {0.f, 0.f, 0.f, 0.f, 0.f};
  for (int i = threadIdx.x; i < kNBlk; i += 256) {
    #pragma unroll
    for (int j = 0; j < 5; ++j) vals[j] += partials[i * 5 + j];
  }
  #pragma unroll
  for (int off = 32; off > 0; off >>= 1) {
    #pragma unroll
    for (int j = 0; j < 5; ++j) vals[j] += __shfl_down(vals[j], off, 64);
  }
  const int wave = threadIdx.x >> 6, lane = threadIdx.x & 63;
  if (lane == 0) {
    #pragma unroll
    for (int j = 0; j < 5; ++j) s_red[wave][j] = vals[j];
  }
  __syncthreads();
  if (threadIdx.x == 0) {
    float tot[5];
    #pragma unroll
    for (int j = 0; j < 5; ++j)
      tot[j] = s_red[0][j] + s_red[1][j] + s_red[2][j] + s_red[3][j];
    const float nv = fmaxf(tot[3], 1.f);
    const float np = fmaxf(tot[4], 1.f);
    out[0] = tot[0] / nv;  // cls_loss
    out[1] = tot[1] / nv;  // box_loss (ref divides by n_valid)
    out[2] = tot[2] / np;  // score_loss
  }
}

extern "C" void kernel_launch(void* const* d_in, const int* in_sizes, int n_in,
                              void* d_out, int out_size, void* d_ws, size_t ws_size,
                              hipStream_t stream) {
  (void)in_sizes; (void)n_in; (void)out_size; (void)ws_size;
  const float* proposals    = (const float*)d_in[0];
  const float* gt_boxes     = (const float*)d_in[1];
  const int*   gt_labels    = (const int*)d_in[2];
  const float* class_logits = (const float*)d_in[3];
  const float* box_reg      = (const float*)d_in[4];
  const float* box_scores   = (const float*)d_in[5];
  float* partials = (float*)d_ws;   // kNBlk*5 floats = 81 KB
  float* out = (float*)d_out;

  roi_partials<<<kNBlk, kBlk, 0, stream>>>(proposals, gt_boxes, gt_labels,
                                           class_logits, box_reg, box_scores,
                                           partials);
  roi_finalize<<<1, 256, 0, stream>>>(partials, out);
}

// Round 3
// 23.127 us; speedup vs baseline: 1.5480x; 1.1175x over previous
//
#include <hip/hip_runtime.h>
#include <math.h>

namespace {
constexpr int kB = 8;
constexpr int kP = 8000;
constexpr int kG = 100;
constexpr int kT = kP + kG;     // 8100
constexpr int kC = 81;
constexpr int kBlk = 256;
constexpr int kLanes = 16;                         // lanes per row-group
constexpr int kRowsPerBlk = kBlk / kLanes;         // 16 rows per block
constexpr int kRows = kB * kT;                     // 64800
constexpr int kNBlk = kRows / kRowsPerBlk;         // 4050 blocks
constexpr int kStride = 4096;                      // padded partials stride
constexpr float kFG = 0.5f;
constexpr float kBG = 0.4f;
constexpr float kBeta = 1.0f / 9.0f;
}

// One 16-lane group per row. gt boxes/areas/labels staged in LDS per block.
// Fast-path math: v_rcp for IoU division, __expf/__logf for CE.
// Partials written transposed [5][kStride] for a coalesced finalize.
__global__ __launch_bounds__(kBlk) void roi_partials(
    const float* __restrict__ proposals,    // [B,P,4]
    const float* __restrict__ gt_boxes,     // [B,G,4]
    const int*   __restrict__ gt_labels,    // [B,G]
    const float* __restrict__ class_logits, // [B,T,C]
    const float* __restrict__ box_reg,      // [B,T,C*4]
    const float* __restrict__ box_scores,   // [B,T]
    float* __restrict__ partials)           // [5][kStride]
{
  __shared__ float4 s_gt[kG];
  __shared__ float  s_area[kG];
  __shared__ int    s_lab[kG];
  __shared__ float  s_red[kBlk / 64][5];

  const int l   = threadIdx.x & (kLanes - 1);
  const int grp = threadIdx.x >> 4;
  const int r   = blockIdx.x * kRowsPerBlk + grp;   // global row
  const int b   = r / kT;
  const int t   = r - b * kT;

  // stage gt data for this batch (one batch per block: 16 rows never span b)
  for (int i = threadIdx.x; i < kG; i += kBlk) {
    const float4 g = reinterpret_cast<const float4*>(gt_boxes)[(size_t)b * kG + i];
    s_gt[i] = g;
    s_area[i] = (g.z - g.x) * (g.w - g.y);
    s_lab[i] = gt_labels[b * kG + i];
  }
  __syncthreads();

  // proposal box for this row (rows >= kP are the appended gt boxes)
  const float4 pb = (t < kP)
      ? reinterpret_cast<const float4*>(proposals)[(size_t)b * kP + t]
      : s_gt[t - kP];
  const float area_p = (pb.z - pb.x) * (pb.w - pb.y);

  // --- cooperative IoU argmax over kG gt boxes (LDS reads, rcp divide) ---
  float best = -1.f;
  int bi = 0;
  #pragma unroll
  for (int k = 0; k < (kG + kLanes - 1) / kLanes; ++k) {
    const int g = l + k * kLanes;
    if (g < kG) {
      const float4 gb = s_gt[g];
      float w = fminf(gb.z, pb.z) - fmaxf(gb.x, pb.x);
      float h = fminf(gb.w, pb.w) - fmaxf(gb.y, pb.y);
      w = fmaxf(w, 0.f);
      h = fmaxf(h, 0.f);
      const float inter = w * h;
      const float iou = inter * __builtin_amdgcn_rcpf(s_area[g] + area_p - inter);
      if (iou > best) { best = iou; bi = g; }  // strict >: first-max per lane
    }
  }
  // group argmax reduce, tie-break to smaller index (jnp.argmax first-max)
  #pragma unroll
  for (int m = 8; m >= 1; m >>= 1) {
    const float ob = __shfl_xor(best, m, kLanes);
    const int   oi = __shfl_xor(bi, m, kLanes);
    if (ob > best || (ob == best && oi < bi)) { best = ob; bi = oi; }
  }

  int label = s_lab[bi];
  if (best < kBG) label = 0;
  else if (best < kFG) label = -1;
  const bool valid = label >= 0;
  const bool pos = label > 0;
  const int lab = valid ? label : 0;

  // --- cooperative CE: logsumexp over 81 logits, coalesced 64B segments ---
  float v_nll = 0.f, v_cv = 0.f;
  if (valid) {
    const float* lg = class_logits + (size_t)r * kC;
    float x[6];
    float mx = -INFINITY, xl = 0.f;
    #pragma unroll
    for (int k = 0; k < 6; ++k) {
      const int c = l + k * kLanes;
      x[k] = (c < kC) ? lg[c] : -INFINITY;
      mx = fmaxf(mx, x[k]);
      if (c < kC && c == lab) xl = x[k];
    }
    #pragma unroll
    for (int m = 8; m >= 1; m >>= 1) mx = fmaxf(mx, __shfl_xor(mx, m, kLanes));
    float se = 0.f;
    #pragma unroll
    for (int k = 0; k < 6; ++k) se += __expf(x[k] - mx);  // exp(-inf)=0 pads
    #pragma unroll
    for (int m = 8; m >= 1; m >>= 1) {
      se += __shfl_xor(se, m, kLanes);
      xl += __shfl_xor(xl, m, kLanes);
    }
    v_nll = -(xl - mx - __logf(se));
    v_cv = 1.f;
  }

  // --- box regression + score (lane-0 work) ---
  float v_sl1 = 0.f, v_sc = 0.f, v_cp = 0.f;
  if (pos && l == 0) {
    const float4 gb = s_gt[bi];
    const float ex_w = pb.z - pb.x, ex_h = pb.w - pb.y;
    const float ex_cx = pb.x + 0.5f * ex_w, ex_cy = pb.y + 0.5f * ex_h;
    const float gt_w = gb.z - gb.x, gt_h = gb.w - gb.y;
    const float gt_cx = gb.x + 0.5f * gt_w, gt_cy = gb.y + 0.5f * gt_h;
    const float tx = 10.f * (gt_cx - ex_cx) / ex_w;
    const float ty = 10.f * (gt_cy - ex_cy) / ex_h;
    const float tw = 5.f * logf(gt_w / ex_w);
    const float th = 5.f * logf(gt_h / ex_h);
    const float4 pv =
        reinterpret_cast<const float4*>(box_reg)[(size_t)r * kC + lab];
    const float d0 = fabsf(pv.x - tx), d1 = fabsf(pv.y - ty);
    const float d2 = fabsf(pv.z - tw), d3 = fabsf(pv.w - th);
    float acc = 0.f;
    acc += (d0 < kBeta) ? 0.5f * d0 * d0 / kBeta : d0 - 0.5f * kBeta;
    acc += (d1 < kBeta) ? 0.5f * d1 * d1 / kBeta : d1 - 0.5f * kBeta;
    acc += (d2 < kBeta) ? 0.5f * d2 * d2 / kBeta : d2 - 0.5f * kBeta;
    acc += (d3 < kBeta) ? 0.5f * d3 * d3 / kBeta : d3 - 0.5f * kBeta;
    v_sl1 = acc;
    v_sc = fabsf(box_scores[r] - best);  // score target == matched IoU
    v_cp = 1.f;
  }
  if (l != 0) { v_nll = 0.f; v_cv = 0.f; }  // CE values replicated on lanes

  // deterministic block reduction
  float vals[5] = {v_nll, v_sl1, v_sc, v_cv, v_cp};
  #pragma unroll
  for (int off = 32; off > 0; off >>= 1) {
    #pragma unroll
    for (int j = 0; j < 5; ++j) vals[j] += __shfl_down(vals[j], off, 64);
  }
  const int wave = threadIdx.x >> 6, lane = threadIdx.x & 63;
  if (lane == 0) {
    #pragma unroll
    for (int j = 0; j < 5; ++j) s_red[wave][j] = vals[j];
  }
  __syncthreads();
  if (threadIdx.x == 0) {
    #pragma unroll
    for (int j = 0; j < 5; ++j) {
      float tot = 0.f;
      #pragma unroll
      for (int w = 0; w < kBlk / 64; ++w) tot += s_red[w][j];
      partials[j * kStride + blockIdx.x] = tot;  // transposed layout
    }
  }
}

// 1024 threads, coalesced reads of the transposed partials.
__global__ __launch_bounds__(1024) void roi_finalize(
    const float* __restrict__ partials, float* __restrict__ out) {
  __shared__ float s_red[16][5];
  float vals[5] = {0.f, 0.f, 0.f, 0.f, 0.f};
  #pragma unroll
  for (int k = 0; k < (kNBlk + 1023) / 1024; ++k) {
    const int i = threadIdx.x + k * 1024;
    if (i < kNBlk) {
      #pragma unroll
      for (int j = 0; j < 5; ++j) vals[j] += partials[j * kStride + i];
    }
  }
  #pragma unroll
  for (int off = 32; off > 0; off >>= 1) {
    #pragma unroll
    for (int j = 0; j < 5; ++j) vals[j] += __shfl_down(vals[j], off, 64);
  }
  const int wave = threadIdx.x >> 6, lane = threadIdx.x & 63;
  if (lane == 0) {
    #pragma unroll
    for (int j = 0; j < 5; ++j) s_red[wave][j] = vals[j];
  }
  __syncthreads();
  if (threadIdx.x == 0) {
    float tot[5];
    #pragma unroll
    for (int j = 0; j < 5; ++j) {
      float s = 0.f;
      #pragma unroll
      for (int w = 0; w < 16; ++w) s += s_red[w][j];
      tot[j] = s;
    }
    const float nv = fmaxf(tot[3], 1.f);
    const float np = fmaxf(tot[4], 1.f);
    out[0] = tot[0] / nv;  // cls_loss
    out[1] = tot[1] / nv;  // box_loss (ref divides by n_valid)
    out[2] = tot[2] / np;  // score_loss
  }
}

extern "C" void kernel_launch(void* const* d_in, const int* in_sizes, int n_in,
                              void* d_out, int out_size, void* d_ws, size_t ws_size,
                              hipStream_t stream) {
  (void)in_sizes; (void)n_in; (void)out_size; (void)ws_size;
  const float* proposals    = (const float*)d_in[0];
  const float* gt_boxes     = (const float*)d_in[1];
  const int*   gt_labels    = (const int*)d_in[2];
  const float* class_logits = (const float*)d_in[3];
  const float* box_reg      = (const float*)d_in[4];
  const float* box_scores   = (const float*)d_in[5];
  float* partials = (float*)d_ws;   // 5*kStride floats = 80 KB
  float* out = (float*)d_out;

  roi_partials<<<kNBlk, kBlk, 0, stream>>>(proposals, gt_boxes, gt_labels,
                                           class_logits, box_reg, box_scores,
                                           partials);
  roi_finalize<<<1, 1024, 0, stream>>>(partials, out);
}